// Round 7
// baseline (406.700 us; speedup 1.0000x reference)
//
#include <hip/hip_runtime.h>
#include <hip/hip_bf16.h>

typedef __attribute__((ext_vector_type(8))) short bf16x8;
typedef __attribute__((ext_vector_type(4))) short bf16x4s;
typedef __attribute__((ext_vector_type(4))) float f32x4;
typedef unsigned int u32;

#define DIM 2048
#define NH 32
#define NKV 8
#define HD 64
#define BB 2
#define SS 2048
#define MROWS (BB*SS)     // 4096
#define NQKV 3072         // 2048 q + 512 k + 512 v columns
#define KDIM 2048

__device__ __forceinline__ short f2bf(float f){
  u32 u = __float_as_uint(f);
  u32 r = u + 0x7fffu + ((u >> 16) & 1u);   // RNE
  return (short)(r >> 16);
}
__device__ __forceinline__ float bf2f(short s){
  return __uint_as_float(((u32)(unsigned short)s) << 16);
}

// ---------------- fp32 -> bf16 convert (n4 = n/4) ----------------
__global__ __launch_bounds__(256) void cvt_kernel(const float* __restrict__ in,
                                                  short* __restrict__ out, int n4){
  int i = blockIdx.x*256 + threadIdx.x;
  if (i >= n4) return;
  f32x4 v = ((const f32x4*)in)[i];
  bf16x4s o;
  #pragma unroll
  for (int j=0;j<4;++j) o[j] = f2bf(v[j]);
  ((bf16x4s*)out)[i] = o;
}

// ---------------- RoPE tables: cos/sin[s][i], i<32 ----------------
__global__ __launch_bounds__(256) void ropetab_kernel(float* __restrict__ cosT,
                                                      float* __restrict__ sinT){
  int idx = blockIdx.x*256 + threadIdx.x;
  if (idx >= SS*32) return;
  int s = idx >> 5, i = idx & 31;
  float inv = powf(10000.f, -(float)i * (1.f/32.f));
  float f = (float)s * inv;
  cosT[idx] = cosf(f);
  sinT[idx] = sinf(f);
}

// ---------------- RoPE apply on q (heads 0..31) and k (heads 32..39) in qkv ----------------
__global__ __launch_bounds__(256) void rope_kernel(short* __restrict__ qkv,
                                                   const float* __restrict__ cosT,
                                                   const float* __restrict__ sinT){
  int idx = blockIdx.x*256 + threadIdx.x;
  int i = idx & 31;
  int rest = idx >> 5;
  int head = rest % 40;          // 0..31 q heads, 32..39 k heads; col base = head*64
  int m = rest / 40;
  if (m >= MROWS) return;
  int s = m & (SS-1);
  size_t base = (size_t)m*NQKV + head*64;
  float c  = cosT[(s<<5)+i], sn = sinT[(s<<5)+i];
  float x1 = bf2f(qkv[base+i]), x2 = bf2f(qkv[base+32+i]);
  qkv[base+i]    = f2bf(x1*c - x2*sn);
  qkv[base+32+i] = f2bf(x2*c + x1*sn);
}

// ---------------- GEMM: C[m][n] = sum_k A[m][k]*B[n][k], bf16 in, bf16 out ----------------
// 128x128 tile, BK=32, 4 waves (2x2), 4x4 16x16x32 frags per wave.
// Reg-staged LDS, rows padded to 40 shorts.
__global__ __launch_bounds__(256) void gemm_bt_kernel(const short* __restrict__ A,
                                                      const short* __restrict__ Bm,
                                                      short* __restrict__ C,
                                                      int ldc, int K){
  __shared__ short As[128*40];
  __shared__ short Bs[128*40];
  const int tid = threadIdx.x;
  const int wave = tid >> 6, lane = tid & 63;
  const int g = lane >> 4, r16 = lane & 15;
  const int m0 = blockIdx.y * 128, n0 = blockIdx.x * 128;
  const int wr = wave >> 1, wc = wave & 1;
  f32x4 acc[4][4] = {};
  for (int k0 = 0; k0 < K; k0 += 32){
    #pragma unroll
    for (int it = 0; it < 2; ++it){
      int t = tid + it*256;                  // 0..511
      int row = t >> 2, kc = t & 3;          // [128 rows][4 chunks of 8 bf16]
      *(bf16x8*)&As[row*40 + kc*8] = *(const bf16x8*)&A [(size_t)(m0+row)*K + k0 + kc*8];
      *(bf16x8*)&Bs[row*40 + kc*8] = *(const bf16x8*)&Bm[(size_t)(n0+row)*K + k0 + kc*8];
    }
    __syncthreads();
    bf16x8 a[4], b[4];
    #pragma unroll
    for (int i=0;i<4;++i)
      a[i] = *(const bf16x8*)&As[(wr*64 + i*16 + r16)*40 + g*8];
    #pragma unroll
    for (int j=0;j<4;++j)
      b[j] = *(const bf16x8*)&Bs[(wc*64 + j*16 + r16)*40 + g*8];
    #pragma unroll
    for (int i=0;i<4;++i)
      #pragma unroll
      for (int j=0;j<4;++j)
        acc[i][j] = __builtin_amdgcn_mfma_f32_16x16x32_bf16(a[i], b[j], acc[i][j], 0, 0, 0);
    __syncthreads();
  }
  // C/D layout: col = lane&15, row = (lane>>4)*4 + reg
  #pragma unroll
  for (int i=0;i<4;++i)
    #pragma unroll
    for (int j=0;j<4;++j)
      #pragma unroll
      for (int r=0;r<4;++r){
        int row = m0 + wr*64 + i*16 + g*4 + r;
        int col = n0 + wc*64 + j*16 + r16;
        C[(size_t)row*ldc + col] = f2bf(acc[i][j][r]);
      }
}

// ---------------- Same GEMM but FP32 output (for the final O-projection) ----------------
__global__ __launch_bounds__(256) void gemm_btf_kernel(const short* __restrict__ A,
                                                       const short* __restrict__ Bm,
                                                       float* __restrict__ C,
                                                       int ldc, int K){
  __shared__ short As[128*40];
  __shared__ short Bs[128*40];
  const int tid = threadIdx.x;
  const int wave = tid >> 6, lane = tid & 63;
  const int g = lane >> 4, r16 = lane & 15;
  const int m0 = blockIdx.y * 128, n0 = blockIdx.x * 128;
  const int wr = wave >> 1, wc = wave & 1;
  f32x4 acc[4][4] = {};
  for (int k0 = 0; k0 < K; k0 += 32){
    #pragma unroll
    for (int it = 0; it < 2; ++it){
      int t = tid + it*256;
      int row = t >> 2, kc = t & 3;
      *(bf16x8*)&As[row*40 + kc*8] = *(const bf16x8*)&A [(size_t)(m0+row)*K + k0 + kc*8];
      *(bf16x8*)&Bs[row*40 + kc*8] = *(const bf16x8*)&Bm[(size_t)(n0+row)*K + k0 + kc*8];
    }
    __syncthreads();
    bf16x8 a[4], b[4];
    #pragma unroll
    for (int i=0;i<4;++i)
      a[i] = *(const bf16x8*)&As[(wr*64 + i*16 + r16)*40 + g*8];
    #pragma unroll
    for (int j=0;j<4;++j)
      b[j] = *(const bf16x8*)&Bs[(wc*64 + j*16 + r16)*40 + g*8];
    #pragma unroll
    for (int i=0;i<4;++i)
      #pragma unroll
      for (int j=0;j<4;++j)
        acc[i][j] = __builtin_amdgcn_mfma_f32_16x16x32_bf16(a[i], b[j], acc[i][j], 0, 0, 0);
    __syncthreads();
  }
  #pragma unroll
  for (int i=0;i<4;++i)
    #pragma unroll
    for (int j=0;j<4;++j)
      #pragma unroll
      for (int r=0;r<4;++r){
        int row = m0 + wr*64 + i*16 + g*4 + r;
        int col = n0 + wc*64 + j*16 + r16;
        C[(size_t)row*ldc + col] = acc[i][j][r];   // fp32 out
      }
}

// ---------------- Flash attention, QBLK=64 (wave-per-16-rows), KVBLK=64 ----------------
// Reg-staged padded LDS (validated ≡ naive scalar attention in rounds 4/5).
__global__ __launch_bounds__(256) void attn_kernel(const short* __restrict__ qkv,
                                                   short* __restrict__ outb){
  __shared__ short Ks2[64*68];      // K rows [key][d], pad 64->68
  __shared__ short Vt2[64*72];      // V^T [d][key], pad 64->72
  __shared__ short Ps[4*16*72];     // per-wave P[16 q][64 key] pad->72
  const int tid = threadIdx.x;
  const int wave = tid >> 6, lane = tid & 63;
  const int g = lane >> 4, r16 = lane & 15;
  const int qt = blockIdx.x, h = blockIdx.y, b = blockIdx.z;
  const int hkv = h >> 2;                       // GQA repeat_interleave: h//4
  const size_t row0 = (size_t)b * SS;
  const int qrow0 = qt*64 + wave*16;
  const short* qbase = qkv + (row0 + qrow0)*NQKV + h*HD;
  const short* kbase = qkv + row0*NQKV + DIM + hkv*HD;
  const short* vbase = qkv + row0*NQKV + DIM + NKV*HD + hkv*HD;

  bf16x8 qf[2];
  #pragma unroll
  for (int kk=0;kk<2;++kk)
    qf[kk] = *(const bf16x8*)(qbase + (size_t)r16*NQKV + kk*32 + g*8);

  f32x4 oacc[4] = {};
  float mrow[4], lrow[4];
  #pragma unroll
  for (int r=0;r<4;++r){ mrow[r] = -1e30f; lrow[r] = 0.f; }

  short* pw = &Ps[wave*1152];

  for (int s0 = 0; s0 < SS; s0 += 64){
    #pragma unroll
    for (int cc=0; cc<2; ++cc){
      int c = tid + cc*256;
      int key = c >> 3, kc = c & 7;
      *(bf16x8*)&Ks2[key*68 + kc*8] = *(const bf16x8*)(kbase + (size_t)(s0+key)*NQKV + kc*8);
    }
    #pragma unroll
    for (int cc=0; cc<2; ++cc){
      int c = tid + cc*256;
      int key = c & 63, dc = c >> 6;
      bf16x8 vv = *(const bf16x8*)(vbase + (size_t)(s0+key)*NQKV + dc*8);
      #pragma unroll
      for (int i=0;i<8;++i) Vt2[(dc*8+i)*72 + key] = vv[i];
    }
    __syncthreads();

    // QK^T -> S[16 q][64 key]
    f32x4 sacc[4];
    #pragma unroll
    for (int t=0;t<4;++t){
      f32x4 cacc = {};
      #pragma unroll
      for (int kk=0;kk<2;++kk){
        const bf16x8 kb = *(const bf16x8*)&Ks2[(t*16 + r16)*68 + (kk*4+g)*8];
        cacc = __builtin_amdgcn_mfma_f32_16x16x32_bf16(qf[kk], kb, cacc, 0,0,0);
      }
      sacc[t] = cacc;
    }

    // online softmax (1/sqrt(64)=0.125 folded into exp args)
    float pmax[4];
    #pragma unroll
    for (int r=0;r<4;++r){
      float mx = fmaxf(fmaxf(sacc[0][r], sacc[1][r]), fmaxf(sacc[2][r], sacc[3][r]));
      mx = fmaxf(mx, __shfl_xor(mx, 1));
      mx = fmaxf(mx, __shfl_xor(mx, 2));
      mx = fmaxf(mx, __shfl_xor(mx, 4));
      mx = fmaxf(mx, __shfl_xor(mx, 8));
      pmax[r] = mx;
    }
    float rsum[4];
    #pragma unroll
    for (int r=0;r<4;++r){
      float mnew = fmaxf(mrow[r], pmax[r]);
      float scale = __expf((mrow[r] - mnew)*0.125f);
      mrow[r] = mnew;
      lrow[r] *= scale;
      #pragma unroll
      for (int j=0;j<4;++j) oacc[j][r] *= scale;
      rsum[r] = 0.f;
    }
    #pragma unroll
    for (int t=0;t<4;++t){
      #pragma unroll
      for (int r=0;r<4;++r){
        float p = __expf((sacc[t][r] - mrow[r])*0.125f);
        rsum[r] += p;
        pw[(4*g + r)*72 + t*16 + r16] = f2bf(p);
      }
    }
    #pragma unroll
    for (int r=0;r<4;++r){
      float sm = rsum[r];
      sm += __shfl_xor(sm, 1);
      sm += __shfl_xor(sm, 2);
      sm += __shfl_xor(sm, 4);
      sm += __shfl_xor(sm, 8);
      lrow[r] += sm;
    }

    // PV: O[16 q][64 d] += P[16][64] * V[64][64]
    #pragma unroll
    for (int kk=0;kk<2;++kk){
      bf16x8 pa = *(const bf16x8*)(pw + r16*72 + kk*32 + g*8);
      #pragma unroll
      for (int j=0;j<4;++j){
        bf16x8 vb = *(const bf16x8*)&Vt2[(j*16 + r16)*72 + kk*32 + g*8];
        oacc[j] = __builtin_amdgcn_mfma_f32_16x16x32_bf16(pa, vb, oacc[j], 0,0,0);
      }
    }
    __syncthreads();
  }

  #pragma unroll
  for (int j=0;j<4;++j)
    #pragma unroll
    for (int r=0;r<4;++r){
      float o = oacc[j][r] / lrow[r];
      outb[(row0 + qrow0 + 4*g + r)*(size_t)DIM + h*HD + j*16 + r16] = f2bf(o);
    }
}

extern "C" void kernel_launch(void* const* d_in, const int* in_sizes, int n_in,
                              void* d_out, int out_size, void* d_ws, size_t ws_size,
                              hipStream_t stream){
  const float* x  = (const float*)d_in[0];
  const float* wq = (const float*)d_in[1];
  const float* wk = (const float*)d_in[2];
  const float* wv = (const float*)d_in[3];
  const float* wo = (const float*)d_in[4];
  float* outf = (float*)d_out;   // FP32 output [4096, 2048] (reference output dtype)

  // Workspace (48.5 MB, time-shared):
  //   [0,16M):  wqkvb (12M, phases 0-1) THEN attnb (16M, phases 3-4)
  //   [16,24M): wob
  //   [24,48M): qkv
  //   [48,48.5M): cos/sin tables
  //   xb lives in d_out (16MB bf16; d_out is 32MB fp32; dead before final GEMM writes)
  char* ws = (char*)d_ws;
  short* wqkvb = (short*)(ws);
  short* attnb = (short*)(ws);
  short* wob   = (short*)(ws + 16777216);
  short* qkv   = (short*)(ws + 25165824);
  float* cosT  = (float*)(ws + 50331648);
  float* sinT  = (float*)(ws + 50593792);
  short* xb    = (short*)d_out;

  cvt_kernel<<<(MROWS*KDIM/4+255)/256, 256, 0, stream>>>(x,  xb,    MROWS*KDIM/4);
  cvt_kernel<<<(2048*2048/4+255)/256, 256, 0, stream>>>(wq, wqkvb, 2048*2048/4);
  cvt_kernel<<<(512*2048/4+255)/256,  256, 0, stream>>>(wk, wqkvb + 2048*2048, 512*2048/4);
  cvt_kernel<<<(512*2048/4+255)/256,  256, 0, stream>>>(wv, wqkvb + 2560*2048, 512*2048/4);
  cvt_kernel<<<(2048*2048/4+255)/256, 256, 0, stream>>>(wo, wob,   2048*2048/4);
  ropetab_kernel<<<(SS*32+255)/256, 256, 0, stream>>>(cosT, sinT);

  // QKV projection: [4096,2048] x [3072,2048]^T -> qkv [4096,3072]
  gemm_bt_kernel<<<dim3(NQKV/128, MROWS/128), 256, 0, stream>>>(xb, wqkvb, qkv, NQKV, KDIM);
  rope_kernel<<<(MROWS*40*32)/256, 256, 0, stream>>>(qkv, cosT, sinT);
  // attention (writes attnb, which aliases the now-dead wqkvb)
  attn_kernel<<<dim3(SS/64, NH, BB), 256, 0, stream>>>(qkv, attnb);
  // O projection: [4096,2048] x [2048,2048]^T -> d_out as FP32 (xb now dead)
  gemm_btf_kernel<<<dim3(DIM/128, MROWS/128), 256, 0, stream>>>(attnb, wob, outf, DIM, KDIM);
}

// Round 8
// 351.887 us; speedup vs baseline: 1.1558x; 1.1558x over previous
//
#include <hip/hip_runtime.h>
#include <hip/hip_bf16.h>

typedef __attribute__((ext_vector_type(8))) short bf16x8;
typedef __attribute__((ext_vector_type(4))) short bf16x4s;
typedef __attribute__((ext_vector_type(4))) float f32x4;
typedef unsigned int u32;

#define DIM 2048
#define NH 32
#define NKV 8
#define HD 64
#define BB 2
#define SS 2048
#define MROWS (BB*SS)     // 4096
#define NQKV 3072         // 2048 q + 512 k + 512 v columns
#define KDIM 2048

__device__ __forceinline__ short f2bf(float f){
  u32 u = __float_as_uint(f);
  u32 r = u + 0x7fffu + ((u >> 16) & 1u);   // RNE
  return (short)(r >> 16);
}
__device__ __forceinline__ float bf2f(short s){
  return __uint_as_float(((u32)(unsigned short)s) << 16);
}

// async global->LDS, 16B per lane; dest must be wave-uniform base (+lane*16 implicit)
__device__ __forceinline__ void gload16(const void* g, void* l){
  __builtin_amdgcn_global_load_lds((const __attribute__((address_space(1))) u32*)g,
                                   (__attribute__((address_space(3))) u32*)l, 16, 0, 0);
}

// ---------------- fp32 -> bf16 convert (n4 = n/4) ----------------
__global__ __launch_bounds__(256) void cvt_kernel(const float* __restrict__ in,
                                                  short* __restrict__ out, int n4){
  int i = blockIdx.x*256 + threadIdx.x;
  if (i >= n4) return;
  f32x4 v = ((const f32x4*)in)[i];
  bf16x4s o;
  #pragma unroll
  for (int j=0;j<4;++j) o[j] = f2bf(v[j]);
  ((bf16x4s*)out)[i] = o;
}

// ---------------- RoPE tables: cos/sin[s][i], i<32 ----------------
__global__ __launch_bounds__(256) void ropetab_kernel(float* __restrict__ cosT,
                                                      float* __restrict__ sinT){
  int idx = blockIdx.x*256 + threadIdx.x;
  if (idx >= SS*32) return;
  int s = idx >> 5, i = idx & 31;
  float inv = powf(10000.f, -(float)i * (1.f/32.f));
  float f = (float)s * inv;
  cosT[idx] = cosf(f);
  sinT[idx] = sinf(f);
}

// ---------------- RoPE apply on q (heads 0..31) and k (heads 32..39) in qkv ----------------
__global__ __launch_bounds__(256) void rope_kernel(short* __restrict__ qkv,
                                                   const float* __restrict__ cosT,
                                                   const float* __restrict__ sinT){
  int idx = blockIdx.x*256 + threadIdx.x;
  int i = idx & 31;
  int rest = idx >> 5;
  int head = rest % 40;          // 0..31 q heads, 32..39 k heads; col base = head*64
  int m = rest / 40;
  if (m >= MROWS) return;
  int s = m & (SS-1);
  size_t base = (size_t)m*NQKV + head*64;
  float c  = cosT[(s<<5)+i], sn = sinT[(s<<5)+i];
  float x1 = bf2f(qkv[base+i]), x2 = bf2f(qkv[base+32+i]);
  qkv[base+i]    = f2bf(x1*c - x2*sn);
  qkv[base+32+i] = f2bf(x2*c + x1*sn);
}

// ---------------- V^T materialization: Vtg[b][hkv][d=64][S] = V[b][s][hkv][d] ----------------
__global__ __launch_bounds__(256) void vT_kernel(const short* __restrict__ qkv,
                                                 short* __restrict__ Vtg){
  __shared__ short T[64*72];
  const int tid = threadIdx.x;
  const int s0 = blockIdx.x*64, hkv = blockIdx.y, b = blockIdx.z;
  const short* vbase = qkv + (size_t)b*SS*NQKV + DIM + NKV*HD + hkv*HD;
  #pragma unroll
  for (int cc=0; cc<2; ++cc){
    int c = tid + cc*256;
    int s = c >> 3, dc = c & 7;
    bf16x8 v = *(const bf16x8*)(vbase + (size_t)(s0+s)*NQKV + dc*8);
    #pragma unroll
    for (int i=0;i<8;++i) T[(dc*8+i)*72 + s] = v[i];
  }
  __syncthreads();
  short* obase = Vtg + ((size_t)(b*NKV + hkv)*64)*SS;
  #pragma unroll
  for (int cc=0; cc<2; ++cc){
    int c = tid + cc*256;
    int d = c >> 3, sc = c & 7;
    *(bf16x8*)(obase + (size_t)d*SS + s0 + sc*8) = *(const bf16x8*)&T[d*72 + sc*8];
  }
}

// ---------------- GEMM: C[m][n] = sum_k A[m][k]*B[n][k], bf16 in, bf16 out ----------------
// m97 structure: 128x128 tile, BK=32, gload_lds staging (validated r3==r4).
__global__ __launch_bounds__(256) void gemm_bt_kernel(const short* __restrict__ A,
                                                      const short* __restrict__ Bm,
                                                      short* __restrict__ C,
                                                      int ldc, int K){
  __shared__ short As[128*32];
  __shared__ short Bs[128*32];
  const int tid = threadIdx.x;
  const int wave = tid >> 6, lane = tid & 63;
  const int g = lane >> 4, r16 = lane & 15;
  const int m0 = blockIdx.y * 128, n0 = blockIdx.x * 128;
  const int wr = wave >> 1, wc = wave & 1;
  f32x4 acc[4][4] = {};
  for (int k0 = 0; k0 < K; k0 += 32){
    #pragma unroll
    for (int c2 = 0; c2 < 2; ++c2){
      int ch = (wave*2 + c2)*64 + lane;
      int row = ch >> 2, kc = ch & 3;
      gload16(A  + (size_t)(m0+row)*K + k0 + kc*8, (char*)As + (wave*2+c2)*1024);
      gload16(Bm + (size_t)(n0+row)*K + k0 + kc*8, (char*)Bs + (wave*2+c2)*1024);
    }
    __syncthreads();
    bf16x8 a[4], b[4];
    #pragma unroll
    for (int i=0;i<4;++i)
      a[i] = *(const bf16x8*)&As[(wr*64 + i*16 + r16)*32 + g*8];
    #pragma unroll
    for (int j=0;j<4;++j)
      b[j] = *(const bf16x8*)&Bs[(wc*64 + j*16 + r16)*32 + g*8];
    #pragma unroll
    for (int i=0;i<4;++i)
      #pragma unroll
      for (int j=0;j<4;++j)
        acc[i][j] = __builtin_amdgcn_mfma_f32_16x16x32_bf16(a[i], b[j], acc[i][j], 0, 0, 0);
    __syncthreads();
  }
  #pragma unroll
  for (int i=0;i<4;++i)
    #pragma unroll
    for (int j=0;j<4;++j)
      #pragma unroll
      for (int r=0;r<4;++r){
        int row = m0 + wr*64 + i*16 + g*4 + r;
        int col = n0 + wc*64 + j*16 + r16;
        C[(size_t)row*ldc + col] = f2bf(acc[i][j][r]);
      }
}

// ---------------- Same GEMM, FP32 output (final O-projection) ----------------
__global__ __launch_bounds__(256) void gemm_btf_kernel(const short* __restrict__ A,
                                                       const short* __restrict__ Bm,
                                                       float* __restrict__ C,
                                                       int ldc, int K){
  __shared__ short As[128*32];
  __shared__ short Bs[128*32];
  const int tid = threadIdx.x;
  const int wave = tid >> 6, lane = tid & 63;
  const int g = lane >> 4, r16 = lane & 15;
  const int m0 = blockIdx.y * 128, n0 = blockIdx.x * 128;
  const int wr = wave >> 1, wc = wave & 1;
  f32x4 acc[4][4] = {};
  for (int k0 = 0; k0 < K; k0 += 32){
    #pragma unroll
    for (int c2 = 0; c2 < 2; ++c2){
      int ch = (wave*2 + c2)*64 + lane;
      int row = ch >> 2, kc = ch & 3;
      gload16(A  + (size_t)(m0+row)*K + k0 + kc*8, (char*)As + (wave*2+c2)*1024);
      gload16(Bm + (size_t)(n0+row)*K + k0 + kc*8, (char*)Bs + (wave*2+c2)*1024);
    }
    __syncthreads();
    bf16x8 a[4], b[4];
    #pragma unroll
    for (int i=0;i<4;++i)
      a[i] = *(const bf16x8*)&As[(wr*64 + i*16 + r16)*32 + g*8];
    #pragma unroll
    for (int j=0;j<4;++j)
      b[j] = *(const bf16x8*)&Bs[(wc*64 + j*16 + r16)*32 + g*8];
    #pragma unroll
    for (int i=0;i<4;++i)
      #pragma unroll
      for (int j=0;j<4;++j)
        acc[i][j] = __builtin_amdgcn_mfma_f32_16x16x32_bf16(a[i], b[j], acc[i][j], 0, 0, 0);
    __syncthreads();
  }
  #pragma unroll
  for (int i=0;i<4;++i)
    #pragma unroll
    for (int j=0;j<4;++j)
      #pragma unroll
      for (int r=0;r<4;++r){
        int row = m0 + wr*64 + i*16 + g*4 + r;
        int col = n0 + wc*64 + j*16 + r16;
        C[(size_t)row*ldc + col] = acc[i][j][r];
      }
}

// ---------------- Flash attention: QBLK=128 (8 waves x 16 q-rows), KVBLK=64 ----------------
// K and V^T staged via gload_lds with both-sides XOR swizzle (r3==r4 validated pattern).
__global__ __launch_bounds__(512) void attn_kernel(const short* __restrict__ qkv,
                                                   const short* __restrict__ Vtg,
                                                   short* __restrict__ outb){
  __shared__ short Ks[64*64];       // [key][d], XOR-swizzled 16B chunks
  __shared__ short Vt[64*64];       // V^T [d][key], XOR-swizzled 16B chunks
  __shared__ short Ps[8*16*72];     // per-wave P[16 q][64 key] pad->72
  const int tid = threadIdx.x;
  const int wave = tid >> 6, lane = tid & 63;
  const int g = lane >> 4, r16 = lane & 15;
  const int qt = blockIdx.x, h = blockIdx.y, b = blockIdx.z;
  const int hkv = h >> 2;                       // GQA repeat_interleave: h//4
  const size_t row0 = (size_t)b * SS;
  const int qrow0 = qt*128 + wave*16;
  const short* qbase  = qkv + (row0 + qrow0)*NQKV + h*HD;
  const short* kbase  = qkv + row0*NQKV + DIM + hkv*HD;
  const short* vtbase = Vtg + ((size_t)(b*NKV + hkv)*64)*SS;

  // Q fragments hoisted: A[row=r16][k=kk*32+8g+j]
  bf16x8 qf[2];
  #pragma unroll
  for (int kk=0;kk<2;++kk)
    qf[kk] = *(const bf16x8*)(qbase + (size_t)r16*NQKV + kk*32 + g*8);

  f32x4 oacc[4] = {};
  float mrow[4], lrow[4];
  #pragma unroll
  for (int r=0;r<4;++r){ mrow[r] = -1e30f; lrow[r] = 0.f; }

  short* pw = &Ps[wave*1152];

  for (int s0 = 0; s0 < SS; s0 += 64){
    // ---- stage K tile [64 key][64 d]: one 16B chunk per thread, source pre-swizzled ----
    {
      int key = tid >> 3, c3 = tid & 7;
      gload16(kbase + (size_t)(s0+key)*NQKV + (((c3 ^ (key&7))) << 3),
              (char*)Ks + wave*1024);
      // ---- stage V^T tile [64 d][64 key] ----
      int d = tid >> 3;
      gload16(vtbase + (size_t)d*SS + s0 + (((c3 ^ (d&7))) << 3),
              (char*)Vt + wave*1024);
    }
    __syncthreads();

    // QK^T -> S[16 q][64 key]
    f32x4 sacc[4];
    #pragma unroll
    for (int t=0;t<4;++t){
      f32x4 cacc = {};
      #pragma unroll
      for (int kk=0;kk<2;++kk){
        int row = t*16 + r16;
        const bf16x8* kp = (const bf16x8*)((const char*)Ks + row*128 +
                            ((((kk<<2)+g) ^ (row&7)) << 4));
        cacc = __builtin_amdgcn_mfma_f32_16x16x32_bf16(qf[kk], *kp, cacc, 0,0,0);
      }
      sacc[t] = cacc;
    }

    // online softmax (1/sqrt(64)=0.125 folded into exp args)
    float pmax[4];
    #pragma unroll
    for (int r=0;r<4;++r){
      float mx = fmaxf(fmaxf(sacc[0][r], sacc[1][r]), fmaxf(sacc[2][r], sacc[3][r]));
      mx = fmaxf(mx, __shfl_xor(mx, 1));
      mx = fmaxf(mx, __shfl_xor(mx, 2));
      mx = fmaxf(mx, __shfl_xor(mx, 4));
      mx = fmaxf(mx, __shfl_xor(mx, 8));
      pmax[r] = mx;
    }
    float rsum[4];
    #pragma unroll
    for (int r=0;r<4;++r){
      float mnew = fmaxf(mrow[r], pmax[r]);
      float scale = __expf((mrow[r] - mnew)*0.125f);
      mrow[r] = mnew;
      lrow[r] *= scale;
      #pragma unroll
      for (int j=0;j<4;++j) oacc[j][r] *= scale;
      rsum[r] = 0.f;
    }
    #pragma unroll
    for (int t=0;t<4;++t){
      #pragma unroll
      for (int r=0;r<4;++r){
        float p = __expf((sacc[t][r] - mrow[r])*0.125f);
        rsum[r] += p;
        pw[(4*g + r)*72 + t*16 + r16] = f2bf(p);
      }
    }
    #pragma unroll
    for (int r=0;r<4;++r){
      float sm = rsum[r];
      sm += __shfl_xor(sm, 1);
      sm += __shfl_xor(sm, 2);
      sm += __shfl_xor(sm, 4);
      sm += __shfl_xor(sm, 8);
      lrow[r] += sm;
    }

    // PV: O[16 q][64 d] += P[16][64] * V[64][64]
    // A-frag: P[row=r16][k]; B-frag: V^T[d=j*16+r16][key-chunk swizzled]
    #pragma unroll
    for (int kk=0;kk<2;++kk){
      bf16x8 pa = *(const bf16x8*)(pw + r16*72 + kk*32 + g*8);
      #pragma unroll
      for (int j=0;j<4;++j){
        int d = j*16 + r16;
        const bf16x8* vp = (const bf16x8*)((const char*)Vt + d*128 +
                            ((((kk<<2)+g) ^ (d&7)) << 4));
        oacc[j] = __builtin_amdgcn_mfma_f32_16x16x32_bf16(pa, *vp, oacc[j], 0,0,0);
      }
    }
    __syncthreads();
  }

  // epilogue: normalize and store bf16 [B*S][2048]
  #pragma unroll
  for (int j=0;j<4;++j)
    #pragma unroll
    for (int r=0;r<4;++r){
      float o = oacc[j][r] / lrow[r];
      outb[(row0 + qrow0 + 4*g + r)*(size_t)DIM + h*HD + j*16 + r16] = f2bf(o);
    }
}

extern "C" void kernel_launch(void* const* d_in, const int* in_sizes, int n_in,
                              void* d_out, int out_size, void* d_ws, size_t ws_size,
                              hipStream_t stream){
  const float* x  = (const float*)d_in[0];
  const float* wq = (const float*)d_in[1];
  const float* wk = (const float*)d_in[2];
  const float* wv = (const float*)d_in[3];
  const float* wo = (const float*)d_in[4];
  float* outf = (float*)d_out;   // FP32 output [4096, 2048]

  // Workspace (48.5 MB, proven size; time-shared):
  //   [0,16M):  wqkvb (12M, early) THEN attnb (16M, late)
  //   [16,24M): wob
  //   [24,48M): qkv
  //   [48,48.5M): cos/sin tables
  // d_out (32MB fp32) time-shared: [0,16M) xb bf16 (dead after QKV GEMM),
  //   [16,20M) Vtg bf16 V^T (dead before final GEMM writes d_out).
  char* ws = (char*)d_ws;
  short* wqkvb = (short*)(ws);
  short* attnb = (short*)(ws);
  short* wob   = (short*)(ws + 16777216);
  short* qkv   = (short*)(ws + 25165824);
  float* cosT  = (float*)(ws + 50331648);
  float* sinT  = (float*)(ws + 50593792);
  short* xb    = (short*)d_out;
  short* Vtg   = (short*)((char*)d_out + 16777216);

  cvt_kernel<<<(MROWS*KDIM/4+255)/256, 256, 0, stream>>>(x,  xb,    MROWS*KDIM/4);
  cvt_kernel<<<(2048*2048/4+255)/256, 256, 0, stream>>>(wq, wqkvb, 2048*2048/4);
  cvt_kernel<<<(512*2048/4+255)/256,  256, 0, stream>>>(wk, wqkvb + 2048*2048, 512*2048/4);
  cvt_kernel<<<(512*2048/4+255)/256,  256, 0, stream>>>(wv, wqkvb + 2560*2048, 512*2048/4);
  cvt_kernel<<<(2048*2048/4+255)/256, 256, 0, stream>>>(wo, wob,   2048*2048/4);
  ropetab_kernel<<<(SS*32+255)/256, 256, 0, stream>>>(cosT, sinT);

  // QKV projection: [4096,2048] x [3072,2048]^T -> qkv [4096,3072]
  gemm_bt_kernel<<<dim3(NQKV/128, MROWS/128), 256, 0, stream>>>(xb, wqkvb, qkv, NQKV, KDIM);
  rope_kernel<<<(MROWS*40*32)/256, 256, 0, stream>>>(qkv, cosT, sinT);
  // materialize V^T once per (b,hkv)
  vT_kernel<<<dim3(SS/64, NKV, BB), 256, 0, stream>>>(qkv, Vtg);
  // attention (writes attnb, aliasing the now-dead wqkvb)
  attn_kernel<<<dim3(SS/128, NH, BB), 512, 0, stream>>>(qkv, Vtg, attnb);
  // O projection: [4096,2048] x [2048,2048]^T -> d_out as FP32
  gemm_btf_kernel<<<dim3(DIM/128, MROWS/128), 256, 0, stream>>>(attnb, wob, outf, DIM, KDIM);
}

// Round 9
// 280.614 us; speedup vs baseline: 1.4493x; 1.2540x over previous
//
#include <hip/hip_runtime.h>
#include <hip/hip_bf16.h>

typedef __attribute__((ext_vector_type(8))) short bf16x8;
typedef __attribute__((ext_vector_type(4))) short bf16x4s;
typedef __attribute__((ext_vector_type(4))) float f32x4;
typedef __attribute__((ext_vector_type(2))) unsigned int u32x2;
typedef unsigned int u32;

#define DIM 2048
#define NH 32
#define NKV 8
#define HD 64
#define BB 2
#define SS 2048
#define MROWS (BB*SS)     // 4096
#define NQKV 3072         // 2048 q + 512 k + 512 v columns
#define KDIM 2048
#define L2E 1.44269504f

__device__ __forceinline__ short f2bf(float f){
  u32 u = __float_as_uint(f);
  u32 r = u + 0x7fffu + ((u >> 16) & 1u);   // RNE
  return (short)(r >> 16);
}
__device__ __forceinline__ float bf2f(short s){
  return __uint_as_float(((u32)(unsigned short)s) << 16);
}

// async global->LDS, 16B per lane; dest must be wave-uniform base (+lane*16 implicit)
__device__ __forceinline__ void gload16(const void* g, void* l){
  __builtin_amdgcn_global_load_lds((const __attribute__((address_space(1))) u32*)g,
                                   (__attribute__((address_space(3))) u32*)l, 16, 0, 0);
}

// ---------------- fp32 -> bf16 convert (n4 = n/4) ----------------
__global__ __launch_bounds__(256) void cvt_kernel(const float* __restrict__ in,
                                                  short* __restrict__ out, int n4){
  int i = blockIdx.x*256 + threadIdx.x;
  if (i >= n4) return;
  f32x4 v = ((const f32x4*)in)[i];
  bf16x4s o;
  #pragma unroll
  for (int j=0;j<4;++j) o[j] = f2bf(v[j]);
  ((bf16x4s*)out)[i] = o;
}

// ---------------- RoPE tables: cos/sin[s][i], i<32 ----------------
__global__ __launch_bounds__(256) void ropetab_kernel(float* __restrict__ cosT,
                                                      float* __restrict__ sinT){
  int idx = blockIdx.x*256 + threadIdx.x;
  if (idx >= SS*32) return;
  int s = idx >> 5, i = idx & 31;
  float inv = powf(10000.f, -(float)i * (1.f/32.f));
  float f = (float)s * inv;
  cosT[idx] = cosf(f);
  sinT[idx] = sinf(f);
}

// ---------------- RoPE apply; q heads additionally pre-scaled by 1/sqrt(HD)=0.125 ----------------
__global__ __launch_bounds__(256) void rope_kernel(short* __restrict__ qkv,
                                                   const float* __restrict__ cosT,
                                                   const float* __restrict__ sinT){
  int idx = blockIdx.x*256 + threadIdx.x;
  int i = idx & 31;
  int rest = idx >> 5;
  int head = rest % 40;          // 0..31 q heads, 32..39 k heads; col base = head*64
  int m = rest / 40;
  if (m >= MROWS) return;
  int s = m & (SS-1);
  size_t base = (size_t)m*NQKV + head*64;
  float sc = (head < 32) ? 0.125f : 1.0f;   // fold attention scale into q (exact in bf16)
  float c  = cosT[(s<<5)+i], sn = sinT[(s<<5)+i];
  float x1 = bf2f(qkv[base+i]), x2 = bf2f(qkv[base+32+i]);
  qkv[base+i]    = f2bf((x1*c - x2*sn)*sc);
  qkv[base+32+i] = f2bf((x2*c + x1*sn)*sc);
}

// ---------------- V^T materialization: Vtg[b][hkv][d=64][S] = V[b][s][hkv][d] ----------------
__global__ __launch_bounds__(256) void vT_kernel(const short* __restrict__ qkv,
                                                 short* __restrict__ Vtg){
  __shared__ short T[64*72];
  const int tid = threadIdx.x;
  const int s0 = blockIdx.x*64, hkv = blockIdx.y, b = blockIdx.z;
  const short* vbase = qkv + (size_t)b*SS*NQKV + DIM + NKV*HD + hkv*HD;
  #pragma unroll
  for (int cc=0; cc<2; ++cc){
    int c = tid + cc*256;
    int s = c >> 3, dc = c & 7;
    bf16x8 v = *(const bf16x8*)(vbase + (size_t)(s0+s)*NQKV + dc*8);
    #pragma unroll
    for (int i=0;i<8;++i) T[(dc*8+i)*72 + s] = v[i];
  }
  __syncthreads();
  short* obase = Vtg + ((size_t)(b*NKV + hkv)*64)*SS;
  #pragma unroll
  for (int cc=0; cc<2; ++cc){
    int c = tid + cc*256;
    int d = c >> 3, sc = c & 7;
    *(bf16x8*)(obase + (size_t)d*SS + s0 + sc*8) = *(const bf16x8*)&T[d*72 + sc*8];
  }
}

// ---------------- GEMM: C[m][n] = sum_k A[m][k]*B[n][k], bf16 in, bf16 out ----------------
__global__ __launch_bounds__(256) void gemm_bt_kernel(const short* __restrict__ A,
                                                      const short* __restrict__ Bm,
                                                      short* __restrict__ C,
                                                      int ldc, int K){
  __shared__ short As[128*32];
  __shared__ short Bs[128*32];
  const int tid = threadIdx.x;
  const int wave = tid >> 6, lane = tid & 63;
  const int g = lane >> 4, r16 = lane & 15;
  const int m0 = blockIdx.y * 128, n0 = blockIdx.x * 128;
  const int wr = wave >> 1, wc = wave & 1;
  f32x4 acc[4][4] = {};
  for (int k0 = 0; k0 < K; k0 += 32){
    #pragma unroll
    for (int c2 = 0; c2 < 2; ++c2){
      int ch = (wave*2 + c2)*64 + lane;
      int row = ch >> 2, kc = ch & 3;
      gload16(A  + (size_t)(m0+row)*K + k0 + kc*8, (char*)As + (wave*2+c2)*1024);
      gload16(Bm + (size_t)(n0+row)*K + k0 + kc*8, (char*)Bs + (wave*2+c2)*1024);
    }
    __syncthreads();
    bf16x8 a[4], b[4];
    #pragma unroll
    for (int i=0;i<4;++i)
      a[i] = *(const bf16x8*)&As[(wr*64 + i*16 + r16)*32 + g*8];
    #pragma unroll
    for (int j=0;j<4;++j)
      b[j] = *(const bf16x8*)&Bs[(wc*64 + j*16 + r16)*32 + g*8];
    #pragma unroll
    for (int i=0;i<4;++i)
      #pragma unroll
      for (int j=0;j<4;++j)
        acc[i][j] = __builtin_amdgcn_mfma_f32_16x16x32_bf16(a[i], b[j], acc[i][j], 0, 0, 0);
    __syncthreads();
  }
  #pragma unroll
  for (int i=0;i<4;++i)
    #pragma unroll
    for (int j=0;j<4;++j)
      #pragma unroll
      for (int r=0;r<4;++r){
        int row = m0 + wr*64 + i*16 + g*4 + r;
        int col = n0 + wc*64 + j*16 + r16;
        C[(size_t)row*ldc + col] = f2bf(acc[i][j][r]);
      }
}

// ---------------- Same GEMM, FP32 output (final O-projection) ----------------
__global__ __launch_bounds__(256) void gemm_btf_kernel(const short* __restrict__ A,
                                                       const short* __restrict__ Bm,
                                                       float* __restrict__ C,
                                                       int ldc, int K){
  __shared__ short As[128*32];
  __shared__ short Bs[128*32];
  const int tid = threadIdx.x;
  const int wave = tid >> 6, lane = tid & 63;
  const int g = lane >> 4, r16 = lane & 15;
  const int m0 = blockIdx.y * 128, n0 = blockIdx.x * 128;
  const int wr = wave >> 1, wc = wave & 1;
  f32x4 acc[4][4] = {};
  for (int k0 = 0; k0 < K; k0 += 32){
    #pragma unroll
    for (int c2 = 0; c2 < 2; ++c2){
      int ch = (wave*2 + c2)*64 + lane;
      int row = ch >> 2, kc = ch & 3;
      gload16(A  + (size_t)(m0+row)*K + k0 + kc*8, (char*)As + (wave*2+c2)*1024);
      gload16(Bm + (size_t)(n0+row)*K + k0 + kc*8, (char*)Bs + (wave*2+c2)*1024);
    }
    __syncthreads();
    bf16x8 a[4], b[4];
    #pragma unroll
    for (int i=0;i<4;++i)
      a[i] = *(const bf16x8*)&As[(wr*64 + i*16 + r16)*32 + g*8];
    #pragma unroll
    for (int j=0;j<4;++j)
      b[j] = *(const bf16x8*)&Bs[(wc*64 + j*16 + r16)*32 + g*8];
    #pragma unroll
    for (int i=0;i<4;++i)
      #pragma unroll
      for (int j=0;j<4;++j)
        acc[i][j] = __builtin_amdgcn_mfma_f32_16x16x32_bf16(a[i], b[j], acc[i][j], 0, 0, 0);
    __syncthreads();
  }
  #pragma unroll
  for (int i=0;i<4;++i)
    #pragma unroll
    for (int j=0;j<4;++j)
      #pragma unroll
      for (int r=0;r<4;++r){
        int row = m0 + wr*64 + i*16 + g*4 + r;
        int col = n0 + wc*64 + j*16 + r16;
        C[(size_t)row*ldc + col] = acc[i][j][r];
      }
}

// ---------------- Flash attention: QBLK=128 (8 waves x 16 q-rows), KVBLK=64 ----------------
// Swapped operands: QK^T computes S^T (lane-local q=r16), PV computes O^T.
// K and V^T staged via gload_lds with both-sides XOR swizzle (r8-validated).
__global__ __launch_bounds__(512) void attn_kernel(const short* __restrict__ qkv,
                                                   const short* __restrict__ Vtg,
                                                   short* __restrict__ outb){
  __shared__ short Ks[64*64];       // [key][d], XOR-swizzled 16B chunks
  __shared__ short Vt[64*64];       // V^T [d][key], XOR-swizzled 16B chunks
  __shared__ short Ps[8*16*72];     // per-wave P^T as [q=16][key 64] pad->72
  const int tid = threadIdx.x;
  const int wave = tid >> 6, lane = tid & 63;
  const int g = lane >> 4, r16 = lane & 15;
  const int qt = blockIdx.x, h = blockIdx.y, b = blockIdx.z;
  const int hkv = h >> 2;                       // GQA repeat_interleave: h//4
  const size_t row0 = (size_t)b * SS;
  const int qrow0 = qt*128 + wave*16;
  const short* qbase  = qkv + (row0 + qrow0)*NQKV + h*HD;
  const short* kbase  = qkv + row0*NQKV + DIM + hkv*HD;
  const short* vtbase = Vtg + ((size_t)(b*NKV + hkv)*64)*SS;

  // Q fragments (B-operand): lane holds Q[q=r16][d=kk*32+g*8+j] (pre-scaled by 0.125)
  bf16x8 qf[2];
  #pragma unroll
  for (int kk=0;kk<2;++kk)
    qf[kk] = *(const bf16x8*)(qbase + (size_t)r16*NQKV + kk*32 + g*8);

  // O^T accumulator: oaccT[j][r] = O[d=j*16+g*4+r][q=r16]
  f32x4 oaccT[4] = {};
  float M = -6.0e29f;      // running max in log2 units (M = m*log2e), per-lane scalar (q=r16)
  float lrow = 0.f;

  short* pwv = &Ps[wave*16*72];

  for (int s0 = 0; s0 < SS; s0 += 64){
    // ---- stage K [64 key][64 d] and V^T [64 d][64 key]: pre-swizzled source ----
    {
      int key = tid >> 3, c3 = tid & 7;
      gload16(kbase + (size_t)(s0+key)*NQKV + (((c3 ^ (key&7))) << 3),
              (char*)Ks + wave*1024);
      int d = tid >> 3;
      gload16(vtbase + (size_t)d*SS + s0 + (((c3 ^ (d&7))) << 3),
              (char*)Vt + wave*1024);
    }
    __syncthreads();

    // QK^T (swapped) -> S^T: sacc[t][r] = S[key=t*16+g*4+r][q=r16]
    f32x4 sacc[4];
    #pragma unroll
    for (int t=0;t<4;++t){
      f32x4 cacc = {};
      #pragma unroll
      for (int kk=0;kk<2;++kk){
        int row = t*16 + r16;
        const bf16x8* kp = (const bf16x8*)((const char*)Ks + row*128 +
                            ((((kk<<2)+g) ^ (row&7)) << 4));
        cacc = __builtin_amdgcn_mfma_f32_16x16x32_bf16(*kp, qf[kk], cacc, 0,0,0);
      }
      sacc[t] = cacc;
    }

    // ---- in-register online softmax, per-lane scalar state (q = r16) ----
    float mx = sacc[0][0];
    #pragma unroll
    for (int t=0;t<4;++t)
      #pragma unroll
      for (int r=0;r<4;++r) mx = fmaxf(mx, sacc[t][r]);
    mx = fmaxf(mx, __shfl_xor(mx, 16));
    mx = fmaxf(mx, __shfl_xor(mx, 32));
    float Mnew = fmaxf(M, mx * L2E);
    float al;
    { float a = M - Mnew; asm("v_exp_f32 %0, %1" : "=v"(al) : "v"(a)); }
    // p = 2^(s*L2E - Mnew), packed to bf16 pairs
    float sum = 0.f;
    u32 pb[4][2];
    #pragma unroll
    for (int t=0;t<4;++t){
      float p[4];
      #pragma unroll
      for (int r=0;r<4;++r){
        float a = fmaf(sacc[t][r], L2E, -Mnew);
        asm("v_exp_f32 %0, %1" : "=v"(p[r]) : "v"(a));
        sum += p[r];
      }
      asm("v_cvt_pk_bf16_f32 %0, %1, %2" : "=v"(pb[t][0]) : "v"(p[0]), "v"(p[1]));
      asm("v_cvt_pk_bf16_f32 %0, %1, %2" : "=v"(pb[t][1]) : "v"(p[2]), "v"(p[3]));
    }
    sum += __shfl_xor(sum, 16);
    sum += __shfl_xor(sum, 32);
    lrow = lrow*al + sum;
    M = Mnew;
    #pragma unroll
    for (int j=0;j<4;++j)
      #pragma unroll
      for (int r=0;r<4;++r) oaccT[j][r] *= al;
    // write P^T slice: Ps[q=r16][key t*16+g*4 .. +3]  (ds_write_b64 x4)
    #pragma unroll
    for (int t=0;t<4;++t)
      *(u32x2*)&pwv[r16*72 + t*16 + g*4] = (u32x2){pb[t][0], pb[t][1]};

    // PV (swapped): O^T[d][q] += V^T[d][key] * P^T[key][q]
    // B-frag: P[q=r16][keys 32kk+g*8..+7]; A-frag: V^T[d=j*16+r16][same keys] (swizzled chunk)
    #pragma unroll
    for (int kk=0;kk<2;++kk){
      bf16x8 pf = *(const bf16x8*)&pwv[r16*72 + 32*kk + g*8];
      #pragma unroll
      for (int j=0;j<4;++j){
        int d = j*16 + r16;
        const bf16x8* vp = (const bf16x8*)((const char*)Vt + d*128 +
                            ((((kk<<2)+g) ^ (d&7)) << 4));
        oaccT[j] = __builtin_amdgcn_mfma_f32_16x16x32_bf16(*vp, pf, oaccT[j], 0,0,0);
      }
    }
    __syncthreads();
  }

  // epilogue: out[q=r16][d=j*16+g*4+r] = O^T/l, 4x 8B stores
  float inv = 1.0f / lrow;
  short* orow = outb + (row0 + qrow0 + r16)*(size_t)DIM + h*HD;
  #pragma unroll
  for (int j=0;j<4;++j){
    bf16x4s ov;
    #pragma unroll
    for (int r=0;r<4;++r) ov[r] = f2bf(oaccT[j][r]*inv);
    *(bf16x4s*)&orow[j*16 + g*4] = ov;
  }
}

extern "C" void kernel_launch(void* const* d_in, const int* in_sizes, int n_in,
                              void* d_out, int out_size, void* d_ws, size_t ws_size,
                              hipStream_t stream){
  const float* x  = (const float*)d_in[0];
  const float* wq = (const float*)d_in[1];
  const float* wk = (const float*)d_in[2];
  const float* wv = (const float*)d_in[3];
  const float* wo = (const float*)d_in[4];
  float* outf = (float*)d_out;   // FP32 output [4096, 2048]

  // Workspace (48.5 MB, time-shared):
  //   [0,16M):  wqkvb (12M, early) THEN attnb (16M, late)
  //   [16,24M): wob
  //   [24,48M): qkv
  //   [48,48.5M): cos/sin tables
  // d_out (32MB fp32) time-shared: [0,16M) xb bf16 (dead after QKV GEMM),
  //   [16,20M) Vtg bf16 V^T (dead before final GEMM writes d_out).
  char* ws = (char*)d_ws;
  short* wqkvb = (short*)(ws);
  short* attnb = (short*)(ws);
  short* wob   = (short*)(ws + 16777216);
  short* qkv   = (short*)(ws + 25165824);
  float* cosT  = (float*)(ws + 50331648);
  float* sinT  = (float*)(ws + 50593792);
  short* xb    = (short*)d_out;
  short* Vtg   = (short*)((char*)d_out + 16777216);

  cvt_kernel<<<(MROWS*KDIM/4+255)/256, 256, 0, stream>>>(x,  xb,    MROWS*KDIM/4);
  cvt_kernel<<<(2048*2048/4+255)/256, 256, 0, stream>>>(wq, wqkvb, 2048*2048/4);
  cvt_kernel<<<(512*2048/4+255)/256,  256, 0, stream>>>(wk, wqkvb + 2048*2048, 512*2048/4);
  cvt_kernel<<<(512*2048/4+255)/256,  256, 0, stream>>>(wv, wqkvb + 2560*2048, 512*2048/4);
  cvt_kernel<<<(2048*2048/4+255)/256, 256, 0, stream>>>(wo, wob,   2048*2048/4);
  ropetab_kernel<<<(SS*32+255)/256, 256, 0, stream>>>(cosT, sinT);

  // QKV projection: [4096,2048] x [3072,2048]^T -> qkv [4096,3072]
  gemm_bt_kernel<<<dim3(NQKV/128, MROWS/128), 256, 0, stream>>>(xb, wqkvb, qkv, NQKV, KDIM);
  rope_kernel<<<(MROWS*40*32)/256, 256, 0, stream>>>(qkv, cosT, sinT);
  // materialize V^T once per (b,hkv)
  vT_kernel<<<dim3(SS/64, NKV, BB), 256, 0, stream>>>(qkv, Vtg);
  // attention (writes attnb, aliasing the now-dead wqkvb)
  attn_kernel<<<dim3(SS/128, NH, BB), 512, 0, stream>>>(qkv, Vtg, attnb);
  // O projection: [4096,2048] x [2048,2048]^T -> d_out as FP32
  gemm_btf_kernel<<<dim3(DIM/128, MROWS/128), 256, 0, stream>>>(attnb, wob, outf, DIM, KDIM);
}

// Round 10
// 251.157 us; speedup vs baseline: 1.6193x; 1.1173x over previous
//
#include <hip/hip_runtime.h>
#include <hip/hip_bf16.h>

typedef __attribute__((ext_vector_type(8))) short bf16x8;
typedef __attribute__((ext_vector_type(4))) short bf16x4s;
typedef __attribute__((ext_vector_type(4))) float f32x4;
typedef __attribute__((ext_vector_type(2))) unsigned int u32x2;
typedef unsigned int u32;

#define DIM 2048
#define NH 32
#define NKV 8
#define HD 64
#define BB 2
#define SS 2048
#define MROWS (BB*SS)     // 4096
#define NQKV 3072         // 2048 q + 512 k + 512 v columns
#define KDIM 2048
#define L2E 1.44269504f

__device__ __forceinline__ short f2bf(float f){
  u32 u = __float_as_uint(f);
  u32 r = u + 0x7fffu + ((u >> 16) & 1u);   // RNE
  return (short)(r >> 16);
}
__device__ __forceinline__ float bf2f(short s){
  return __uint_as_float(((u32)(unsigned short)s) << 16);
}

// async global->LDS, 16B per lane; dest must be wave-uniform base (+lane*16 implicit)
__device__ __forceinline__ void gload16(const void* g, void* l){
  __builtin_amdgcn_global_load_lds((const __attribute__((address_space(1))) u32*)g,
                                   (__attribute__((address_space(3))) u32*)l, 16, 0, 0);
}

// ---------------- fused fp32 -> bf16 convert of all 5 inputs (1 launch) ----------------
// n4 block ranges: x[0,8192) wq[8192,12288) wk[12288,13312) wv[13312,14336) wo[14336,18432)
__global__ __launch_bounds__(256) void cvt_all_kernel(const float* __restrict__ x,
                                                      const float* __restrict__ wq,
                                                      const float* __restrict__ wk,
                                                      const float* __restrict__ wv,
                                                      const float* __restrict__ wo,
                                                      short* __restrict__ xb,
                                                      short* __restrict__ wqkvb,
                                                      short* __restrict__ wob){
  int bid = blockIdx.x;
  int i = bid*256 + threadIdx.x;
  const float* src; short* dst; int off;
  if      (bid <  8192){ src = x;  dst = xb;              off = 0; }
  else if (bid < 12288){ src = wq; dst = wqkvb;           off = 2097152; }
  else if (bid < 13312){ src = wk; dst = wqkvb+2048*2048; off = 3145728; }
  else if (bid < 14336){ src = wv; dst = wqkvb+2560*2048; off = 3407872; }
  else                 { src = wo; dst = wob;             off = 3670016; }
  int j = i - off;
  f32x4 v = ((const f32x4*)src)[j];
  bf16x4s o;
  #pragma unroll
  for (int t=0;t<4;++t) o[t] = f2bf(v[t]);
  ((bf16x4s*)dst)[j] = o;
}

// ---------------- RoPE tables: cos/sin[s][i], i<32 ----------------
__global__ __launch_bounds__(256) void ropetab_kernel(float* __restrict__ cosT,
                                                      float* __restrict__ sinT){
  int idx = blockIdx.x*256 + threadIdx.x;
  if (idx >= SS*32) return;
  int s = idx >> 5, i = idx & 31;
  float inv = powf(10000.f, -(float)i * (1.f/32.f));
  float f = (float)s * inv;
  cosT[idx] = cosf(f);
  sinT[idx] = sinf(f);
}

// ---------------- V^T materialization: Vtg[b][hkv][d=64][S] = V[b][s][hkv][d] ----------------
__global__ __launch_bounds__(256) void vT_kernel(const short* __restrict__ qkv,
                                                 short* __restrict__ Vtg){
  __shared__ short T[64*72];
  const int tid = threadIdx.x;
  const int s0 = blockIdx.x*64, hkv = blockIdx.y, b = blockIdx.z;
  const short* vbase = qkv + (size_t)b*SS*NQKV + DIM + NKV*HD + hkv*HD;
  #pragma unroll
  for (int cc=0; cc<2; ++cc){
    int c = tid + cc*256;
    int s = c >> 3, dc = c & 7;
    bf16x8 v = *(const bf16x8*)(vbase + (size_t)(s0+s)*NQKV + dc*8);
    #pragma unroll
    for (int i=0;i<8;++i) T[(dc*8+i)*72 + s] = v[i];
  }
  __syncthreads();
  short* obase = Vtg + ((size_t)(b*NKV + hkv)*64)*SS;
  #pragma unroll
  for (int cc=0; cc<2; ++cc){
    int c = tid + cc*256;
    int d = c >> 3, sc = c & 7;
    *(bf16x8*)(obase + (size_t)d*SS + s0 + sc*8) = *(const bf16x8*)&T[d*72 + sc*8];
  }
}

// ---------------- GEMM (bf16 out) with optional fused RoPE epilogue ----------------
// C[m][n] = sum_k A[m][k]*B[n][k]. 128x128 tile, BK=32, gload_lds staging.
// rope!=0: for cols<2560 apply rotation using cos/sin[s= row&2047][col&31];
//          cols<2048 (q heads) additionally scaled by 0.125.
__global__ __launch_bounds__(256) void gemm_bt_kernel(const short* __restrict__ A,
                                                      const short* __restrict__ Bm,
                                                      short* __restrict__ C,
                                                      int ldc, int K,
                                                      const float* __restrict__ cosT,
                                                      const float* __restrict__ sinT,
                                                      int rope){
  __shared__ short As[128*32];
  __shared__ short Bs[128*32];
  const int tid = threadIdx.x;
  const int wave = tid >> 6, lane = tid & 63;
  const int g = lane >> 4, r16 = lane & 15;
  const int m0 = blockIdx.y * 128, n0 = blockIdx.x * 128;
  const int wr = wave >> 1, wc = wave & 1;
  f32x4 acc[4][4] = {};
  for (int k0 = 0; k0 < K; k0 += 32){
    #pragma unroll
    for (int c2 = 0; c2 < 2; ++c2){
      int ch = (wave*2 + c2)*64 + lane;
      int row = ch >> 2, kc = ch & 3;
      gload16(A  + (size_t)(m0+row)*K + k0 + kc*8, (char*)As + (wave*2+c2)*1024);
      gload16(Bm + (size_t)(n0+row)*K + k0 + kc*8, (char*)Bs + (wave*2+c2)*1024);
    }
    __syncthreads();
    bf16x8 a[4], b[4];
    #pragma unroll
    for (int i=0;i<4;++i)
      a[i] = *(const bf16x8*)&As[(wr*64 + i*16 + r16)*32 + g*8];
    #pragma unroll
    for (int j=0;j<4;++j)
      b[j] = *(const bf16x8*)&Bs[(wc*64 + j*16 + r16)*32 + g*8];
    #pragma unroll
    for (int i=0;i<4;++i)
      #pragma unroll
      for (int j=0;j<4;++j)
        acc[i][j] = __builtin_amdgcn_mfma_f32_16x16x32_bf16(a[i], b[j], acc[i][j], 0, 0, 0);
    __syncthreads();
  }
  if (rope && n0 < 2560){
    // rotation pairs: (col, col+32) = (acc[i][j], acc[i][j+2]) for j in {0,1}
    float qsc = (n0 < 2048) ? 0.125f : 1.0f;   // fold 1/sqrt(HD) into q
    #pragma unroll
    for (int i=0;i<4;++i)
      #pragma unroll
      for (int r=0;r<4;++r){
        int row = m0 + wr*64 + i*16 + g*4 + r;
        int s = row & (SS-1);
        #pragma unroll
        for (int j=0;j<2;++j){
          int col = n0 + wc*64 + j*16 + r16;
          float c  = cosT[(s<<5) + (col&31)];
          float sn = sinT[(s<<5) + (col&31)];
          float x1 = acc[i][j][r], x2 = acc[i][j+2][r];
          C[(size_t)row*ldc + col]      = f2bf((x1*c - x2*sn)*qsc);
          C[(size_t)row*ldc + col + 32] = f2bf((x2*c + x1*sn)*qsc);
        }
      }
  } else {
    #pragma unroll
    for (int i=0;i<4;++i)
      #pragma unroll
      for (int j=0;j<4;++j)
        #pragma unroll
        for (int r=0;r<4;++r){
          int row = m0 + wr*64 + i*16 + g*4 + r;
          int col = n0 + wc*64 + j*16 + r16;
          C[(size_t)row*ldc + col] = f2bf(acc[i][j][r]);
        }
  }
}

// ---------------- Same GEMM, FP32 output (final O-projection) ----------------
__global__ __launch_bounds__(256) void gemm_btf_kernel(const short* __restrict__ A,
                                                       const short* __restrict__ Bm,
                                                       float* __restrict__ C,
                                                       int ldc, int K){
  __shared__ short As[128*32];
  __shared__ short Bs[128*32];
  const int tid = threadIdx.x;
  const int wave = tid >> 6, lane = tid & 63;
  const int g = lane >> 4, r16 = lane & 15;
  const int m0 = blockIdx.y * 128, n0 = blockIdx.x * 128;
  const int wr = wave >> 1, wc = wave & 1;
  f32x4 acc[4][4] = {};
  for (int k0 = 0; k0 < K; k0 += 32){
    #pragma unroll
    for (int c2 = 0; c2 < 2; ++c2){
      int ch = (wave*2 + c2)*64 + lane;
      int row = ch >> 2, kc = ch & 3;
      gload16(A  + (size_t)(m0+row)*K + k0 + kc*8, (char*)As + (wave*2+c2)*1024);
      gload16(Bm + (size_t)(n0+row)*K + k0 + kc*8, (char*)Bs + (wave*2+c2)*1024);
    }
    __syncthreads();
    bf16x8 a[4], b[4];
    #pragma unroll
    for (int i=0;i<4;++i)
      a[i] = *(const bf16x8*)&As[(wr*64 + i*16 + r16)*32 + g*8];
    #pragma unroll
    for (int j=0;j<4;++j)
      b[j] = *(const bf16x8*)&Bs[(wc*64 + j*16 + r16)*32 + g*8];
    #pragma unroll
    for (int i=0;i<4;++i)
      #pragma unroll
      for (int j=0;j<4;++j)
        acc[i][j] = __builtin_amdgcn_mfma_f32_16x16x32_bf16(a[i], b[j], acc[i][j], 0, 0, 0);
    __syncthreads();
  }
  #pragma unroll
  for (int i=0;i<4;++i)
    #pragma unroll
    for (int j=0;j<4;++j)
      #pragma unroll
      for (int r=0;r<4;++r){
        int row = m0 + wr*64 + i*16 + g*4 + r;
        int col = n0 + wc*64 + j*16 + r16;
        C[(size_t)row*ldc + col] = acc[i][j][r];
      }
}

// ---------------- Flash attention: QBLK=128 (8 waves x 16 q), KVBLK=128 ----------------
// Swapped operands (S^T / O^T, lane-local q=r16), in-register softmax, defer-max.
__global__ __launch_bounds__(512) void attn_kernel(const short* __restrict__ qkv,
                                                   const short* __restrict__ Vtg,
                                                   short* __restrict__ outb){
  __shared__ short Ks[128*64];      // [key][d], 8-chunk XOR-swizzled rows (128B)
  __shared__ short Vt[64*128];      // V^T [d][key], 16-chunk XOR-swizzled rows (256B)
  __shared__ short Ps[8*16*72];     // per-wave P^T [q=16][64 keys] pad->72, reused per half
  const int tid = threadIdx.x;
  const int wave = tid >> 6, lane = tid & 63;
  const int g = lane >> 4, r16 = lane & 15;
  const int qt = blockIdx.x, h = blockIdx.y, b = blockIdx.z;
  const int hkv = h >> 2;                       // GQA repeat_interleave: h//4
  const size_t row0 = (size_t)b * SS;
  const int qrow0 = qt*128 + wave*16;
  const short* qbase  = qkv + (row0 + qrow0)*NQKV + h*HD;
  const short* kbase  = qkv + row0*NQKV + DIM + hkv*HD;
  const short* vtbase = Vtg + ((size_t)(b*NKV + hkv)*64)*SS;

  // Q fragments (B-operand): lane holds Q[q=r16][d=kk*32+g*8+j] (pre-scaled by 0.125)
  bf16x8 qf[2];
  #pragma unroll
  for (int kk=0;kk<2;++kk)
    qf[kk] = *(const bf16x8*)(qbase + (size_t)r16*NQKV + kk*32 + g*8);

  f32x4 oaccT[4] = {};     // O^T[d=j*16+g*4+r][q=r16]
  float M = -6.0e29f;      // running max, log2 units, per-lane (q=r16)
  float lrow = 0.f;

  short* pwv = &Ps[wave*16*72];

  for (int s0 = 0; s0 < SS; s0 += 128){
    // ---- stage K [128 key][64 d] and V^T [64 d][128 key]; pre-swizzled sources ----
    #pragma unroll
    for (int c=0;c<2;++c){
      int ch = tid + c*512;
      int krow = ch >> 3, c3 = ch & 7;
      gload16(kbase + (size_t)(s0+krow)*NQKV + ((c3 ^ (krow&7)) << 3),
              (char*)Ks + c*8192 + wave*1024);
      int d = ch >> 4, c16 = ch & 15;
      gload16(vtbase + (size_t)d*SS + s0 + ((c16 ^ (d&15)) << 3),
              (char*)Vt + c*8192 + wave*1024);
    }
    __syncthreads();

    // QK^T (swapped) -> S^T: sacc[t][r] = S[key=t*16+g*4+r][q=r16]
    f32x4 sacc[8];
    #pragma unroll
    for (int t=0;t<8;++t){
      f32x4 cacc = {};
      #pragma unroll
      for (int kk=0;kk<2;++kk){
        int krow = t*16 + r16;
        const bf16x8* kp = (const bf16x8*)((const char*)Ks + krow*128 +
                            ((((kk<<2)+g) ^ (krow&7)) << 4));
        cacc = __builtin_amdgcn_mfma_f32_16x16x32_bf16(*kp, qf[kk], cacc, 0,0,0);
      }
      sacc[t] = cacc;
    }

    // ---- in-register online softmax with defer-max (T13) ----
    float mx = sacc[0][0];
    #pragma unroll
    for (int t=0;t<8;++t)
      #pragma unroll
      for (int r=0;r<4;++r) mx = fmaxf(mx, sacc[t][r]);
    mx = fmaxf(mx, __shfl_xor(mx, 16));
    mx = fmaxf(mx, __shfl_xor(mx, 32));
    float mxl = mx * L2E;
    if (__any(mxl > M + 11.5f)){      // wave-uniform rescale branch
      float Mnew = fmaxf(M, mxl);
      float al;
      { float a = M - Mnew; asm("v_exp_f32 %0, %1" : "=v"(al) : "v"(a)); }
      lrow *= al;
      #pragma unroll
      for (int j=0;j<4;++j)
        #pragma unroll
        for (int r=0;r<4;++r) oaccT[j][r] *= al;
      M = Mnew;
    }
    float sum = 0.f;
    u32 pb[8][2];
    #pragma unroll
    for (int t=0;t<8;++t){
      float p[4];
      #pragma unroll
      for (int r=0;r<4;++r){
        float a = fmaf(sacc[t][r], L2E, -M);
        asm("v_exp_f32 %0, %1" : "=v"(p[r]) : "v"(a));
        sum += p[r];
      }
      asm("v_cvt_pk_bf16_f32 %0, %1, %2" : "=v"(pb[t][0]) : "v"(p[0]), "v"(p[1]));
      asm("v_cvt_pk_bf16_f32 %0, %1, %2" : "=v"(pb[t][1]) : "v"(p[2]), "v"(p[3]));
    }
    sum += __shfl_xor(sum, 16);
    sum += __shfl_xor(sum, 32);
    lrow += sum;

    // ---- PV in two 64-key halves through the per-wave Ps buffer ----
    #pragma unroll
    for (int h2=0;h2<2;++h2){
      #pragma unroll
      for (int t2=0;t2<4;++t2)
        *(u32x2*)&pwv[r16*72 + t2*16 + g*4] = (u32x2){pb[h2*4+t2][0], pb[h2*4+t2][1]};
      #pragma unroll
      for (int kki=0;kki<2;++kki){
        bf16x8 pf = *(const bf16x8*)&pwv[r16*72 + 32*kki + g*8];
        int kkg = h2*2 + kki;          // global key-block 0..3
        #pragma unroll
        for (int j=0;j<4;++j){
          int d = j*16 + r16;
          const bf16x8* vp = (const bf16x8*)((const char*)Vt + d*256 +
                              ((((kkg<<2)+g) ^ (d&15)) << 4));
          oaccT[j] = __builtin_amdgcn_mfma_f32_16x16x32_bf16(*vp, pf, oaccT[j], 0,0,0);
        }
      }
    }
    __syncthreads();
  }

  // epilogue: out[q=r16][d=j*16+g*4+r] = O^T/l
  float inv = 1.0f / lrow;
  short* orow = outb + (row0 + qrow0 + r16)*(size_t)DIM + h*HD;
  #pragma unroll
  for (int j=0;j<4;++j){
    bf16x4s ov;
    #pragma unroll
    for (int r=0;r<4;++r) ov[r] = f2bf(oaccT[j][r]*inv);
    *(bf16x4s*)&orow[j*16 + g*4] = ov;
  }
}

extern "C" void kernel_launch(void* const* d_in, const int* in_sizes, int n_in,
                              void* d_out, int out_size, void* d_ws, size_t ws_size,
                              hipStream_t stream){
  const float* x  = (const float*)d_in[0];
  const float* wq = (const float*)d_in[1];
  const float* wk = (const float*)d_in[2];
  const float* wv = (const float*)d_in[3];
  const float* wo = (const float*)d_in[4];
  float* outf = (float*)d_out;   // FP32 output [4096, 2048]

  // Workspace (48.5 MB, time-shared):
  //   [0,16M):  wqkvb (12M, early) THEN attnb (16M, late)
  //   [16,24M): wob
  //   [24,48M): qkv
  //   [48,48.5M): cos/sin tables
  // d_out (32MB fp32) time-shared: [0,16M) xb bf16 (dead after QKV GEMM),
  //   [16,20M) Vtg bf16 V^T (dead before final GEMM writes d_out).
  char* ws = (char*)d_ws;
  short* wqkvb = (short*)(ws);
  short* attnb = (short*)(ws);
  short* wob   = (short*)(ws + 16777216);
  short* qkv   = (short*)(ws + 25165824);
  float* cosT  = (float*)(ws + 50331648);
  float* sinT  = (float*)(ws + 50593792);
  short* xb    = (short*)d_out;
  short* Vtg   = (short*)((char*)d_out + 16777216);

  cvt_all_kernel<<<18432, 256, 0, stream>>>(x, wq, wk, wv, wo, xb, wqkvb, wob);
  ropetab_kernel<<<256, 256, 0, stream>>>(cosT, sinT);

  // QKV projection with fused RoPE epilogue: [4096,2048] x [3072,2048]^T -> qkv
  gemm_bt_kernel<<<dim3(NQKV/128, MROWS/128), 256, 0, stream>>>(xb, wqkvb, qkv, NQKV, KDIM,
                                                                cosT, sinT, 1);
  // materialize V^T once per (b,hkv)
  vT_kernel<<<dim3(SS/64, NKV, BB), 256, 0, stream>>>(qkv, Vtg);
  // attention (writes attnb, aliasing the now-dead wqkvb)
  attn_kernel<<<dim3(SS/128, NH, BB), 512, 0, stream>>>(qkv, Vtg, attnb);
  // O projection: [4096,2048] x [2048,2048]^T -> d_out as FP32
  gemm_btf_kernel<<<dim3(DIM/128, MROWS/128), 256, 0, stream>>>(attnb, wob, outf, DIM, KDIM);
}